// Round 2
// baseline (1278.010 us; speedup 1.0000x reference)
//
#include <hip/hip_runtime.h>
#include <cstdint>
#include <cstddef>

#define H_DIM 1024
#define F_DIM 4096
#define N_EXP 8
#define N_TOK 8192
#define NK_ASSIGN (N_TOK * 2)
#define MAX_MB 12  // max M-blocks/expert at BM=256 = 3072 tokens; actual ~2048±50 (>20 sigma)

typedef unsigned short u16;
typedef __attribute__((ext_vector_type(8))) short bf16x8;
typedef __attribute__((ext_vector_type(4))) float f32x4;

// RNE float -> bf16 bits (finite inputs only)
__device__ __forceinline__ u16 f2bf(float f) {
  unsigned int u = __float_as_uint(f);
  u += 0x7fffu + ((u >> 16) & 1u);
  return (u16)(u >> 16);
}

// async global->LDS, 16B per lane. lds ptr MUST be wave-uniform (HW adds lane*16).
__device__ __forceinline__ void load16(const u16* g, u16* l) {
  __builtin_amdgcn_global_load_lds(
      (const __attribute__((address_space(1))) void*)g,
      (__attribute__((address_space(3))) void*)l, 16, 0, 0);
}

// ---------------- router: fp32 logits, top-2, renormalized softmax gates ----
__global__ __launch_bounds__(256) void router_kernel(
    const float* __restrict__ x, const float* __restrict__ rw,
    const float* __restrict__ rb, int* __restrict__ topk_idx,
    float* __restrict__ topk_w, int* __restrict__ counts) {
  const int lane = threadIdx.x & 63;
  const int wid = threadIdx.x >> 6;
  const int t = blockIdx.x * 4 + wid;  // one wave per token
  const float4* xr = (const float4*)(x + (size_t)t * H_DIM);
  float acc[N_EXP];
#pragma unroll
  for (int e = 0; e < N_EXP; ++e) acc[e] = 0.f;
#pragma unroll
  for (int j = 0; j < 4; ++j) {
    float4 xv = xr[j * 64 + lane];
#pragma unroll
    for (int e = 0; e < N_EXP; ++e) {
      float4 wv = ((const float4*)(rw + e * H_DIM))[j * 64 + lane];
      acc[e] += xv.x * wv.x + xv.y * wv.y + xv.z * wv.z + xv.w * wv.w;
    }
  }
#pragma unroll
  for (int off = 32; off > 0; off >>= 1) {
#pragma unroll
    for (int e = 0; e < N_EXP; ++e) acc[e] += __shfl_xor(acc[e], off);
  }
  if (lane == 0) {
    float lg[N_EXP];
#pragma unroll
    for (int e = 0; e < N_EXP; ++e) lg[e] = acc[e] + rb[e];
    int i0 = 0;
    float b0 = lg[0];
#pragma unroll
    for (int e = 1; e < N_EXP; ++e)
      if (lg[e] > b0) { b0 = lg[e]; i0 = e; }  // strict > : lowest index wins ties
    int i1 = -1;
    float b1 = -3.4e38f;
#pragma unroll
    for (int e = 0; e < N_EXP; ++e)
      if (e != i0 && lg[e] > b1) { b1 = lg[e]; i1 = e; }
    float w0 = 1.f / (1.f + __expf(b1 - b0));  // p0/(p0+p1)
    topk_idx[2 * t] = i0;
    topk_idx[2 * t + 1] = i1;
    topk_w[2 * t] = w0;
    topk_w[2 * t + 1] = 1.f - w0;
    atomicAdd(&counts[i0], 1);
    atomicAdd(&counts[i1], 1);
  }
}

// ---------------- tiny exclusive scan over 8 counts --------------------------
__global__ void scan_kernel(const int* __restrict__ counts,
                            int* __restrict__ offsets,
                            int* __restrict__ cursors) {
  if (threadIdx.x == 0) {
    int s = 0;
    for (int e = 0; e < N_EXP; ++e) {
      offsets[e] = s;
      s += counts[e];
      cursors[e] = 0;
    }
    offsets[N_EXP] = s;  // == 16384
  }
}

// ---------------- scatter token assignments into expert segments -------------
__global__ __launch_bounds__(256) void scatter_kernel(
    const int* __restrict__ topk_idx, const float* __restrict__ topk_w,
    const int* __restrict__ offsets, int* __restrict__ cursors,
    int* __restrict__ assign_token, float* __restrict__ assign_gate,
    int* __restrict__ slot_of) {
  int t = blockIdx.x * 256 + threadIdx.x;
  if (t >= N_TOK) return;
#pragma unroll
  for (int k = 0; k < 2; ++k) {
    int e = topk_idx[2 * t + k];
    int pos = offsets[e] + atomicAdd(&cursors[e], 1);
    assign_token[pos] = t;
    assign_gate[pos] = topk_w[2 * t + k];
    slot_of[2 * t + k] = pos;  // inverse map for combine
  }
}

// ---------------- fp32 [E][R][C] -> bf16 [E][C][R] (transpose + convert) -----
__global__ __launch_bounds__(256) void transpose_cvt(
    const float* __restrict__ in, u16* __restrict__ out, int R, int C) {
  __shared__ u16 lds[64 * 66];
  const int e = blockIdx.z;
  const float* ip = in + (size_t)e * R * C;
  u16* op = out + (size_t)e * R * C;
  const int c0 = blockIdx.x * 64, r0 = blockIdx.y * 64;
  const int tid = threadIdx.x;
  const int tx = tid & 15, ty = tid >> 4;
#pragma unroll
  for (int i = 0; i < 4; ++i) {
    const int r = ty + i * 16;
    float4 v = *(const float4*)(ip + (size_t)(r0 + r) * C + c0 + tx * 4);
    ushort2 u01, u23;
    u01.x = f2bf(v.x); u01.y = f2bf(v.y);
    u23.x = f2bf(v.z); u23.y = f2bf(v.w);
    *(ushort2*)&lds[r * 66 + tx * 4] = u01;
    *(ushort2*)&lds[r * 66 + tx * 4 + 2] = u23;
  }
  __syncthreads();
  const int lane = tid & 63, wid = tid >> 6;
  const int r8 = lane & 7;
#pragma unroll
  for (int s = 0; s < 2; ++s) {
    const int c = s * 32 + wid * 8 + (lane >> 3);
    union { u16 u[8]; uint4 q; } pk;
#pragma unroll
    for (int k = 0; k < 8; ++k) pk.u[k] = lds[(r8 * 8 + k) * 66 + c];
    *(uint4*)(op + (size_t)(c0 + c) * R + r0 + r8 * 8) = pk.q;
  }
}

// ---------------- gather tokens -> compacted bf16 A ([slot][H]) --------------
__global__ __launch_bounds__(256) void gather_kernel(
    const float* __restrict__ x, const int* __restrict__ assign_token,
    u16* __restrict__ xg) {
  const int lane = threadIdx.x & 63;
  const int s = blockIdx.x * 4 + (threadIdx.x >> 6);  // one wave per slot
  const int t = assign_token[s];
  const float4* xr = (const float4*)(x + (size_t)t * H_DIM);
  u16* o = xg + (size_t)s * H_DIM;
#pragma unroll
  for (int j = 0; j < 4; ++j) {
    float4 v = xr[j * 64 + lane];
    ushort4 u;
    u.x = f2bf(v.x); u.y = f2bf(v.y); u.z = f2bf(v.z); u.w = f2bf(v.w);
    *(ushort4*)(o + (size_t)(j * 64 + lane) * 4) = u;
  }
}

// ---------------- grouped GEMM: C[M][N] = A[M][K] * B[N][K]^T ---------------
// 256x256 tile, BK=64, 8 waves (2M x 4N), each wave 8x4 of 16x16x32 bf16 MFMA.
// Double-buffered STATIC LDS (128 KB), 2-phase: prefetch tile kt+1 while
// computing kt; the single __syncthreads() per K-tile drains vmcnt AFTER the
// MFMA cluster, so staging latency hides under the MFMA (T3 min-2-phase).
// NOTE: static __shared__ (not dynamic) — gfx950 allows 128KB static LDS with
// no runtime opt-in; keeps kernel_launch free of host-side runtime calls
// (graph-capture safe).
// FIRST:  A=xg, B=w1b, epilogue = tanh-gelu -> bf16 store to h
// !FIRST: A=h,  B=w2b, epilogue = *gate, plain fp32 store to y_slot[slot][H]
template <int LDA, int LDB, int LDC, int KT, bool FIRST>
__global__ __launch_bounds__(512, 2) void moe_gemm(
    const u16* __restrict__ Abase, const u16* __restrict__ Bbase,
    u16* __restrict__ hout, float* __restrict__ yout,
    const int* __restrict__ offsets, const float* __restrict__ assign_gate) {
  __shared__ __align__(16) u16 As[2 * 256 * 64];  // 64 KB
  __shared__ __align__(16) u16 Bs[2 * 256 * 64];  // 64 KB
  const int e = blockIdx.z;
  const int row0 = offsets[e];
  const int cnt = offsets[e + 1] - row0;
  const int mbase = blockIdx.y * 256;
  if (mbase >= cnt) return;  // block-uniform early exit
  const int mrem = cnt - mbase;
  const int n0 = blockIdx.x * 256;
  const int tid = threadIdx.x;
  const int lane = tid & 63;
  const int wid = tid >> 6;
  const int wm = wid & 1, wn = wid >> 1;   // wave tile: rows wm*128, cols wn*64
  const u16* A = Abase + (size_t)(row0 + mbase) * LDA;
  const u16* B = Bbase + (size_t)e * ((size_t)H_DIM * F_DIM);
  const int row16 = lane & 15, quad = lane >> 4;
  // staging: each round of 8 load16/wave covers 64 rows x 128B; 4 rounds = 256 rows
  const int srow = wid * 8 + (lane >> 3);  // row within 64-row round
  const int scol = (lane & 7) * 8;         // k-col (elements), 8 lanes x 16B = 128B row

  f32x4 acc[8][4];
#pragma unroll
  for (int i = 0; i < 8; ++i)
#pragma unroll
    for (int j = 0; j < 4; ++j)
#pragma unroll
      for (int r = 0; r < 4; ++r) acc[i][j][r] = 0.f;

  auto stage = [&](int buf, int kt) {
    const int k0 = kt * 64;
#pragma unroll
    for (int i = 0; i < 4; ++i) {
      const int r = i * 64 + srow;
      const int ra = min(r, mrem - 1);  // clamp: stay inside valid A rows
      load16(A + (size_t)ra * LDA + (k0 + scol), As + buf * 16384 + (i * 64 + wid * 8) * 64);
      load16(B + (size_t)(n0 + r) * LDB + (k0 + scol), Bs + buf * 16384 + (i * 64 + wid * 8) * 64);
    }
  };

  auto compute = [&](int buf) {
    const u16* Ab = As + buf * 16384;
    const u16* Bb = Bs + buf * 16384;
#pragma unroll
    for (int ks = 0; ks < 2; ++ks) {
      bf16x8 av[8], bv[4];
#pragma unroll
      for (int mi = 0; mi < 8; ++mi)
        av[mi] = *(const bf16x8*)&Ab[(wm * 128 + mi * 16 + row16) * 64 + ks * 32 + quad * 8];
#pragma unroll
      for (int ni = 0; ni < 4; ++ni)
        bv[ni] = *(const bf16x8*)&Bb[(wn * 64 + ni * 16 + row16) * 64 + ks * 32 + quad * 8];
#pragma unroll
      for (int mi = 0; mi < 8; ++mi)
#pragma unroll
        for (int ni = 0; ni < 4; ++ni)
          acc[mi][ni] =
              __builtin_amdgcn_mfma_f32_16x16x32_bf16(av[mi], bv[ni], acc[mi][ni], 0, 0, 0);
    }
  };

  stage(0, 0);
  __syncthreads();  // drain prologue staging
  int cur = 0;
#pragma unroll 1
  for (int kt = 0; kt < KT - 1; ++kt) {
    stage(cur ^ 1, kt + 1);  // issue next-tile loads BEFORE compute
    compute(cur);
    __syncthreads();         // drains vmcnt(0)+lgkmcnt(0): next tile ready
    cur ^= 1;
  }
  compute(cur);  // last tile, no prefetch, no barrier needed before epilogue

  // C/D layout: col = lane&15 (n), row = quad*4 + reg (m)
  if (FIRST) {
    u16* Cp = hout + (size_t)(row0 + mbase) * LDC + n0;
#pragma unroll
    for (int mi = 0; mi < 8; ++mi) {
#pragma unroll
      for (int r = 0; r < 4; ++r) {
        const int lm = wm * 128 + mi * 16 + quad * 4 + r;
        if (lm < mrem) {
#pragma unroll
          for (int ni = 0; ni < 4; ++ni) {
            float v = acc[mi][ni][r];
            // tanh-approx gelu via sigmoid: v * sigmoid(2*sqrt(2/pi)*(v+0.044715v^3))
            float t = v * (0.7978845608028654f + 0.0356774081363f * v * v);
            v = v / (1.f + __expf(-2.f * t));
            Cp[(size_t)lm * LDC + (wn * 64 + ni * 16 + row16)] = f2bf(v);
          }
        }
      }
    }
  } else {
#pragma unroll
    for (int mi = 0; mi < 8; ++mi) {
#pragma unroll
      for (int r = 0; r < 4; ++r) {
        const int lm = wm * 128 + mi * 16 + quad * 4 + r;
        if (lm < mrem) {
          const int slot = row0 + mbase + lm;
          const float g = assign_gate[slot];
          float* orow = yout + (size_t)slot * LDC + n0;
#pragma unroll
          for (int ni = 0; ni < 4; ++ni)
            orow[wn * 64 + ni * 16 + row16] = acc[mi][ni][r] * g;
        }
      }
    }
  }
}

// ---------------- combine: out[t] = y_slot[s0] + y_slot[s1] ------------------
__global__ __launch_bounds__(256) void combine_kernel(
    const float* __restrict__ ys, const int* __restrict__ slot_of,
    float* __restrict__ out) {
  const int t = blockIdx.x;
  const int s0 = slot_of[2 * t], s1 = slot_of[2 * t + 1];
  const int i = threadIdx.x;
  float4 a = ((const float4*)(ys + (size_t)s0 * H_DIM))[i];
  float4 b = ((const float4*)(ys + (size_t)s1 * H_DIM))[i];
  float4 o;
  o.x = a.x + b.x; o.y = a.y + b.y; o.z = a.z + b.z; o.w = a.w + b.w;
  ((float4*)(out + (size_t)t * H_DIM))[i] = o;
}

extern "C" void kernel_launch(void* const* d_in, const int* in_sizes, int n_in,
                              void* d_out, int out_size, void* d_ws, size_t ws_size,
                              hipStream_t stream) {
  const float* x = (const float*)d_in[0];
  const float* rw = (const float*)d_in[1];
  const float* rb = (const float*)d_in[2];
  const float* w1 = (const float*)d_in[3];
  const float* w2 = (const float*)d_in[4];
  float* out = (float*)d_out;

  char* ws = (char*)d_ws;
  // workspace layout (~302.4 MB total)
  u16* w1b = (u16*)(ws);                        // [E][F][H] bf16   67,108,864 B
  float* y_slot = (float*)(ws);                 // [16384][H] fp32 -- ALIASES w1b
                                                // (w1b dead after GEMM1; GEMM2 writes here)
  u16* w2b = (u16*)(ws + 67108864);             // [E][H][F] bf16   67,108,864 B
  u16* xg = (u16*)(ws + 134217728);             // [16384][H] bf16  33,554,432 B
  u16* h = (u16*)(ws + 167772160);              // [16384][F] bf16 134,217,728 B
  char* meta = ws + 301989888;
  int* counts = (int*)(meta + 0);
  int* cursors = (int*)(meta + 32);
  int* offsets = (int*)(meta + 64);             // 9 ints
  int* topk_idx = (int*)(meta + 128);           // 16384 ints
  float* topk_w = (float*)(meta + 128 + 65536);
  int* assign_token = (int*)(meta + 128 + 131072);
  float* assign_gate = (float*)(meta + 128 + 196608);
  int* slot_of = (int*)(meta + 128 + 262144);

  hipMemsetAsync(counts, 0, 64, stream);  // counts + cursors

  router_kernel<<<N_TOK / 4, 256, 0, stream>>>(x, rw, rb, topk_idx, topk_w, counts);
  scan_kernel<<<1, 64, 0, stream>>>(counts, offsets, cursors);
  scatter_kernel<<<N_TOK / 256, 256, 0, stream>>>(topk_idx, topk_w, offsets, cursors,
                                                  assign_token, assign_gate, slot_of);
  // w1 [E][1024][4096] -> w1b [E][4096][1024]
  transpose_cvt<<<dim3(F_DIM / 64, H_DIM / 64, N_EXP), 256, 0, stream>>>(w1, w1b, H_DIM, F_DIM);
  // w2 [E][4096][1024] -> w2b [E][1024][4096]
  transpose_cvt<<<dim3(H_DIM / 64, F_DIM / 64, N_EXP), 256, 0, stream>>>(w2, w2b, F_DIM, H_DIM);
  gather_kernel<<<NK_ASSIGN / 4, 256, 0, stream>>>(x, assign_token, xg);

  // GEMM1: [cnt_e][1024] @ [4096][1024]^T -> gelu -> h [cnt_e][4096]
  moe_gemm<H_DIM, H_DIM, F_DIM, H_DIM / 64, true>
      <<<dim3(F_DIM / 256, MAX_MB, N_EXP), 512, 0, stream>>>(
          xg, w1b, h, nullptr, offsets, assign_gate);
  // GEMM2: [cnt_e][4096] @ [1024][4096]^T -> *gate -> y_slot [16384][1024]
  moe_gemm<F_DIM, F_DIM, H_DIM, F_DIM / 64, false>
      <<<dim3(H_DIM / 256, MAX_MB, N_EXP), 512, 0, stream>>>(
          h, w2b, nullptr, y_slot, offsets, assign_gate);
  // out[t] = y_slot[slot0(t)] + y_slot[slot1(t)]
  combine_kernel<<<N_TOK, 256, 0, stream>>>(y_slot, slot_of, out);

  (void)in_sizes; (void)n_in; (void)ws_size;
}

// Round 3
// 1247.359 us; speedup vs baseline: 1.0246x; 1.0246x over previous
//
#include <hip/hip_runtime.h>
#include <cstdint>
#include <cstddef>

#define H_DIM 1024
#define F_DIM 4096
#define N_EXP 8
#define N_TOK 8192
#define NK_ASSIGN (N_TOK * 2)
#define MAX_MB 12  // max M-blocks/expert at BM=256 = 3072 tokens; actual ~2048±50 (>20 sigma)

typedef unsigned short u16;
typedef __attribute__((ext_vector_type(8))) short bf16x8;
typedef __attribute__((ext_vector_type(4))) float f32x4;

// RNE float -> bf16 bits (finite inputs only)
__device__ __forceinline__ u16 f2bf(float f) {
  unsigned int u = __float_as_uint(f);
  u += 0x7fffu + ((u >> 16) & 1u);
  return (u16)(u >> 16);
}

// async global->LDS, 16B per lane. lds ptr MUST be wave-uniform (HW adds lane*16).
__device__ __forceinline__ void load16(const u16* g, u16* l) {
  __builtin_amdgcn_global_load_lds(
      (const __attribute__((address_space(1))) void*)g,
      (__attribute__((address_space(3))) void*)l, 16, 0, 0);
}

// ---------------- router: fp32 logits, top-2, renormalized softmax gates ----
__global__ __launch_bounds__(256) void router_kernel(
    const float* __restrict__ x, const float* __restrict__ rw,
    const float* __restrict__ rb, int* __restrict__ topk_idx,
    float* __restrict__ topk_w, int* __restrict__ counts) {
  const int lane = threadIdx.x & 63;
  const int wid = threadIdx.x >> 6;
  const int t = blockIdx.x * 4 + wid;  // one wave per token
  const float4* xr = (const float4*)(x + (size_t)t * H_DIM);
  float acc[N_EXP];
#pragma unroll
  for (int e = 0; e < N_EXP; ++e) acc[e] = 0.f;
#pragma unroll
  for (int j = 0; j < 4; ++j) {
    float4 xv = xr[j * 64 + lane];
#pragma unroll
    for (int e = 0; e < N_EXP; ++e) {
      float4 wv = ((const float4*)(rw + e * H_DIM))[j * 64 + lane];
      acc[e] += xv.x * wv.x + xv.y * wv.y + xv.z * wv.z + xv.w * wv.w;
    }
  }
#pragma unroll
  for (int off = 32; off > 0; off >>= 1) {
#pragma unroll
    for (int e = 0; e < N_EXP; ++e) acc[e] += __shfl_xor(acc[e], off);
  }
  if (lane == 0) {
    float lg[N_EXP];
#pragma unroll
    for (int e = 0; e < N_EXP; ++e) lg[e] = acc[e] + rb[e];
    int i0 = 0;
    float b0 = lg[0];
#pragma unroll
    for (int e = 1; e < N_EXP; ++e)
      if (lg[e] > b0) { b0 = lg[e]; i0 = e; }  // strict > : lowest index wins ties
    int i1 = -1;
    float b1 = -3.4e38f;
#pragma unroll
    for (int e = 0; e < N_EXP; ++e)
      if (e != i0 && lg[e] > b1) { b1 = lg[e]; i1 = e; }
    float w0 = 1.f / (1.f + __expf(b1 - b0));  // p0/(p0+p1)
    topk_idx[2 * t] = i0;
    topk_idx[2 * t + 1] = i1;
    topk_w[2 * t] = w0;
    topk_w[2 * t + 1] = 1.f - w0;
    atomicAdd(&counts[i0], 1);
    atomicAdd(&counts[i1], 1);
  }
}

// ---------------- tiny exclusive scan over 8 counts --------------------------
__global__ void scan_kernel(const int* __restrict__ counts,
                            int* __restrict__ offsets,
                            int* __restrict__ cursors) {
  if (threadIdx.x == 0) {
    int s = 0;
    for (int e = 0; e < N_EXP; ++e) {
      offsets[e] = s;
      s += counts[e];
      cursors[e] = 0;
    }
    offsets[N_EXP] = s;  // == 16384
  }
}

// ---------------- scatter token assignments into expert segments -------------
__global__ __launch_bounds__(256) void scatter_kernel(
    const int* __restrict__ topk_idx, const float* __restrict__ topk_w,
    const int* __restrict__ offsets, int* __restrict__ cursors,
    int* __restrict__ assign_token, float* __restrict__ assign_gate,
    int* __restrict__ slot_of) {
  int t = blockIdx.x * 256 + threadIdx.x;
  if (t >= N_TOK) return;
#pragma unroll
  for (int k = 0; k < 2; ++k) {
    int e = topk_idx[2 * t + k];
    int pos = offsets[e] + atomicAdd(&cursors[e], 1);
    assign_token[pos] = t;
    assign_gate[pos] = topk_w[2 * t + k];
    slot_of[2 * t + k] = pos;  // inverse map for combine
  }
}

// ---------------- fp32 [E][R][C] -> bf16 [E][C][R] (transpose + convert) -----
__global__ __launch_bounds__(256) void transpose_cvt(
    const float* __restrict__ in, u16* __restrict__ out, int R, int C) {
  __shared__ u16 lds[64 * 66];
  const int e = blockIdx.z;
  const float* ip = in + (size_t)e * R * C;
  u16* op = out + (size_t)e * R * C;
  const int c0 = blockIdx.x * 64, r0 = blockIdx.y * 64;
  const int tid = threadIdx.x;
  const int tx = tid & 15, ty = tid >> 4;
#pragma unroll
  for (int i = 0; i < 4; ++i) {
    const int r = ty + i * 16;
    float4 v = *(const float4*)(ip + (size_t)(r0 + r) * C + c0 + tx * 4);
    ushort2 u01, u23;
    u01.x = f2bf(v.x); u01.y = f2bf(v.y);
    u23.x = f2bf(v.z); u23.y = f2bf(v.w);
    *(ushort2*)&lds[r * 66 + tx * 4] = u01;
    *(ushort2*)&lds[r * 66 + tx * 4 + 2] = u23;
  }
  __syncthreads();
  const int lane = tid & 63, wid = tid >> 6;
  const int r8 = lane & 7;
#pragma unroll
  for (int s = 0; s < 2; ++s) {
    const int c = s * 32 + wid * 8 + (lane >> 3);
    union { u16 u[8]; uint4 q; } pk;
#pragma unroll
    for (int k = 0; k < 8; ++k) pk.u[k] = lds[(r8 * 8 + k) * 66 + c];
    *(uint4*)(op + (size_t)(c0 + c) * R + r0 + r8 * 8) = pk.q;
  }
}

// ---------------- gather tokens -> compacted bf16 A ([slot][H]) --------------
__global__ __launch_bounds__(256) void gather_kernel(
    const float* __restrict__ x, const int* __restrict__ assign_token,
    u16* __restrict__ xg) {
  const int lane = threadIdx.x & 63;
  const int s = blockIdx.x * 4 + (threadIdx.x >> 6);  // one wave per slot
  const int t = assign_token[s];
  const float4* xr = (const float4*)(x + (size_t)t * H_DIM);
  u16* o = xg + (size_t)s * H_DIM;
#pragma unroll
  for (int j = 0; j < 4; ++j) {
    float4 v = xr[j * 64 + lane];
    ushort4 u;
    u.x = f2bf(v.x); u.y = f2bf(v.y); u.z = f2bf(v.z); u.w = f2bf(v.w);
    *(ushort4*)(o + (size_t)(j * 64 + lane) * 4) = u;
  }
}

// ---------------- grouped GEMM: C[M][N] = A[M][K] * B[N][K]^T ---------------
// 256x256 tile, BK=32, 8 waves (2M x 4N), each wave 8x4 of 16x16x32 bf16 MFMA.
// TRIPLE-buffered LDS (96 KB), 2-tiles-ahead prefetch with COUNTED vmcnt(8):
// per iter: stage(t+2) -> vmcnt(8) [waits only tile t; t+1,t+2 stay in flight
// across barriers] -> s_barrier -> compute(t) -> s_barrier.  Never drains to 0
// in the loop (T4).  LDS XOR swizzle slot^=(row>>1)&3 applied both-sides
// (pre-swizzled GLOBAL source col in stage, same XOR on ds_read) -> 2-way
// bank access = free (T2, rule #21: global_load_lds dest must stay linear).
// XCD-aware remap (T1): flat id -> (xcd = id&7) owns expert xcd's full panel
// set, so B is HBM-fetched once per XCD and A is XCD-local.
// FIRST:  A=xg, B=w1b, epilogue = tanh-gelu -> bf16 store to h
// !FIRST: A=h,  B=w2b, epilogue = *gate, plain fp32 store to y_slot[slot][H]
template <int LDA, int LDB, int LDC, int KT, int NX, bool FIRST>
__global__ __launch_bounds__(512, 2) void moe_gemm(
    const u16* __restrict__ Abase, const u16* __restrict__ Bbase,
    u16* __restrict__ hout, float* __restrict__ yout,
    const int* __restrict__ offsets, const float* __restrict__ assign_gate) {
  __shared__ __align__(16) u16 As[3 * 8192];  // 3 bufs x 256 rows x 32 k (48 KB)
  __shared__ __align__(16) u16 Bs[3 * 8192];  // 48 KB
  // ---- XCD-aware remap: mb varies fastest within an XCD's slot range ----
  const int bid = blockIdx.x + NX * (blockIdx.y + MAX_MB * blockIdx.z);
  const int xcd = bid & 7;
  const int slot = bid >> 3;
  const int r_ = xcd * (NX * MAX_MB) + slot;
  const int mb = r_ % MAX_MB;
  const int g = r_ / MAX_MB;
  const int n0b = g % NX;
  const int e = g / NX;  // == xcd by construction
  const int row0 = offsets[e];
  const int cnt = offsets[e + 1] - row0;
  const int mbase = mb * 256;
  if (mbase >= cnt) return;  // block-uniform early exit
  const int mrem = cnt - mbase;
  const int n0 = n0b * 256;
  const int tid = threadIdx.x;
  const int lane = tid & 63;
  const int wid = tid >> 6;
  const int wm = wid & 1, wn = wid >> 1;  // wave tile: rows wm*128, cols wn*64
  const u16* A = Abase + (size_t)(row0 + mbase) * LDA;
  const u16* B = Bbase + (size_t)e * ((size_t)H_DIM * F_DIM);
  const int row16 = lane & 15, quad = lane >> 4;

  f32x4 acc[8][4];
#pragma unroll
  for (int i = 0; i < 8; ++i)
#pragma unroll
    for (int j = 0; j < 4; ++j)
#pragma unroll
      for (int r = 0; r < 4; ++r) acc[i][j][r] = 0.f;

  // stage one 256x32 K-tile of A and B into buffer `buf` (4 load16/thread).
  // LDS dest linear; global source column pre-swizzled: LDS[r][sl] holds
  // G[r][sl ^ ((r>>1)&3)].
  auto stage = [&](int buf, int kt) {
    const int k0 = kt * 32;
#pragma unroll
    for (int j = 0; j < 2; ++j) {
      const int L = j * 512 + tid;          // 16B-slot index, 0..1023
      const int r = L >> 2;                 // row 0..255
      const int sl = L & 3;                 // slot in 64B row
      const int cs = (sl ^ ((r >> 1) & 3)) * 8;  // swizzled source col (elems)
      u16* ldsA = As + buf * 8192 + (j * 512 + wid * 64) * 8;  // wave-uniform
      u16* ldsB = Bs + buf * 8192 + (j * 512 + wid * 64) * 8;
      const int ra = min(r, mrem - 1);      // clamp: stay inside valid A rows
      load16(A + (size_t)ra * LDA + k0 + cs, ldsA);
      load16(B + (size_t)(n0 + r) * LDB + k0 + cs, ldsB);
    }
  };

  auto compute = [&](int buf) {
    const u16* Ab = As + buf * 8192;
    const u16* Bb = Bs + buf * 8192;
    bf16x8 av[8], bv[4];
#pragma unroll
    for (int mi = 0; mi < 8; ++mi) {
      const int r = wm * 128 + mi * 16 + row16;
      av[mi] = *(const bf16x8*)&Ab[r * 32 + (quad ^ ((r >> 1) & 3)) * 8];
    }
#pragma unroll
    for (int ni = 0; ni < 4; ++ni) {
      const int r = wn * 64 + ni * 16 + row16;
      bv[ni] = *(const bf16x8*)&Bb[r * 32 + (quad ^ ((r >> 1) & 3)) * 8];
    }
#pragma unroll
    for (int mi = 0; mi < 8; ++mi)
#pragma unroll
      for (int ni = 0; ni < 4; ++ni)
        acc[mi][ni] =
            __builtin_amdgcn_mfma_f32_16x16x32_bf16(av[mi], bv[ni], acc[mi][ni], 0, 0, 0);
  };

  stage(0, 0);
  stage(1, 1);  // 8 loads/thread in flight
  int c0 = 0, c1 = 1, c2 = 2;  // buf of tile t, t+1, t+2
#pragma unroll 1
  for (int t = 0; t < KT; ++t) {
    const int ts = (t + 2 < KT) ? t + 2 : KT - 1;  // tail: harmless re-stage
    stage(c2, ts);  // now <=12 loads/thread outstanding
    // wait until only the newest 8 (tiles t+1, t+2) remain -> tile t landed
    asm volatile("s_waitcnt vmcnt(8)" ::: "memory");
    __builtin_amdgcn_s_barrier();  // all waves: tile t fully in LDS
    compute(c0);
    __builtin_amdgcn_s_barrier();  // all reads of buf c0 done (next iter overwrites it)
    const int tmp = c0; c0 = c1; c1 = c2; c2 = tmp;
  }
  // drain remaining async LDS-DMA before the workgroup can exit
  asm volatile("s_waitcnt vmcnt(0)" ::: "memory");

  // C/D layout: col = lane&15 (n), row = quad*4 + reg (m)
  if (FIRST) {
    u16* Cp = hout + (size_t)(row0 + mbase) * LDC + n0;
#pragma unroll
    for (int mi = 0; mi < 8; ++mi) {
#pragma unroll
      for (int r = 0; r < 4; ++r) {
        const int lm = wm * 128 + mi * 16 + quad * 4 + r;
        if (lm < mrem) {
#pragma unroll
          for (int ni = 0; ni < 4; ++ni) {
            float v = acc[mi][ni][r];
            // tanh-approx gelu via sigmoid: v * sigmoid(2*sqrt(2/pi)*(v+0.044715v^3))
            float t = v * (0.7978845608028654f + 0.0356774081363f * v * v);
            v = v / (1.f + __expf(-2.f * t));
            Cp[(size_t)lm * LDC + (wn * 64 + ni * 16 + row16)] = f2bf(v);
          }
        }
      }
    }
  } else {
#pragma unroll
    for (int mi = 0; mi < 8; ++mi) {
#pragma unroll
      for (int r = 0; r < 4; ++r) {
        const int lm = wm * 128 + mi * 16 + quad * 4 + r;
        if (lm < mrem) {
          const int slot = row0 + mbase + lm;
          const float g = assign_gate[slot];
          float* orow = yout + (size_t)slot * LDC + n0;
#pragma unroll
          for (int ni = 0; ni < 4; ++ni)
            orow[wn * 64 + ni * 16 + row16] = acc[mi][ni][r] * g;
        }
      }
    }
  }
}

// ---------------- combine: out[t] = y_slot[s0] + y_slot[s1] ------------------
__global__ __launch_bounds__(256) void combine_kernel(
    const float* __restrict__ ys, const int* __restrict__ slot_of,
    float* __restrict__ out) {
  const int t = blockIdx.x;
  const int s0 = slot_of[2 * t], s1 = slot_of[2 * t + 1];
  const int i = threadIdx.x;
  float4 a = ((const float4*)(ys + (size_t)s0 * H_DIM))[i];
  float4 b = ((const float4*)(ys + (size_t)s1 * H_DIM))[i];
  float4 o;
  o.x = a.x + b.x; o.y = a.y + b.y; o.z = a.z + b.z; o.w = a.w + b.w;
  ((float4*)(out + (size_t)t * H_DIM))[i] = o;
}

extern "C" void kernel_launch(void* const* d_in, const int* in_sizes, int n_in,
                              void* d_out, int out_size, void* d_ws, size_t ws_size,
                              hipStream_t stream) {
  const float* x = (const float*)d_in[0];
  const float* rw = (const float*)d_in[1];
  const float* rb = (const float*)d_in[2];
  const float* w1 = (const float*)d_in[3];
  const float* w2 = (const float*)d_in[4];
  float* out = (float*)d_out;

  char* ws = (char*)d_ws;
  // workspace layout (~302.4 MB total)
  u16* w1b = (u16*)(ws);                        // [E][F][H] bf16   67,108,864 B
  float* y_slot = (float*)(ws);                 // [16384][H] fp32 -- ALIASES w1b
                                                // (w1b dead after GEMM1; GEMM2 writes here)
  u16* w2b = (u16*)(ws + 67108864);             // [E][H][F] bf16   67,108,864 B
  u16* xg = (u16*)(ws + 134217728);             // [16384][H] bf16  33,554,432 B
  u16* h = (u16*)(ws + 167772160);              // [16384][F] bf16 134,217,728 B
  char* meta = ws + 301989888;
  int* counts = (int*)(meta + 0);
  int* cursors = (int*)(meta + 32);
  int* offsets = (int*)(meta + 64);             // 9 ints
  int* topk_idx = (int*)(meta + 128);           // 16384 ints
  float* topk_w = (float*)(meta + 128 + 65536);
  int* assign_token = (int*)(meta + 128 + 131072);
  float* assign_gate = (float*)(meta + 128 + 196608);
  int* slot_of = (int*)(meta + 128 + 262144);

  hipMemsetAsync(counts, 0, 64, stream);  // counts + cursors

  router_kernel<<<N_TOK / 4, 256, 0, stream>>>(x, rw, rb, topk_idx, topk_w, counts);
  scan_kernel<<<1, 64, 0, stream>>>(counts, offsets, cursors);
  scatter_kernel<<<N_TOK / 256, 256, 0, stream>>>(topk_idx, topk_w, offsets, cursors,
                                                  assign_token, assign_gate, slot_of);
  // w1 [E][1024][4096] -> w1b [E][4096][1024]
  transpose_cvt<<<dim3(F_DIM / 64, H_DIM / 64, N_EXP), 256, 0, stream>>>(w1, w1b, H_DIM, F_DIM);
  // w2 [E][4096][1024] -> w2b [E][1024][4096]
  transpose_cvt<<<dim3(H_DIM / 64, F_DIM / 64, N_EXP), 256, 0, stream>>>(w2, w2b, F_DIM, H_DIM);
  gather_kernel<<<NK_ASSIGN / 4, 256, 0, stream>>>(x, assign_token, xg);

  // GEMM1: [cnt_e][1024] @ [4096][1024]^T -> gelu -> h [cnt_e][4096]
  moe_gemm<H_DIM, H_DIM, F_DIM, H_DIM / 32, F_DIM / 256, true>
      <<<dim3(F_DIM / 256, MAX_MB, N_EXP), 512, 0, stream>>>(
          xg, w1b, h, nullptr, offsets, assign_gate);
  // GEMM2: [cnt_e][4096] @ [1024][4096]^T -> *gate -> y_slot [16384][1024]
  moe_gemm<F_DIM, F_DIM, H_DIM, F_DIM / 32, H_DIM / 256, false>
      <<<dim3(H_DIM / 256, MAX_MB, N_EXP), 512, 0, stream>>>(
          h, w2b, nullptr, y_slot, offsets, assign_gate);
  // out[t] = y_slot[slot0(t)] + y_slot[slot1(t)]
  combine_kernel<<<N_TOK, 256, 0, stream>>>(y_slot, slot_of, out);

  (void)in_sizes; (void)n_in; (void)ws_size;
}

// Round 4
// 803.333 us; speedup vs baseline: 1.5909x; 1.5527x over previous
//
#include <hip/hip_runtime.h>
#include <cstdint>
#include <cstddef>

#define H_DIM 1024
#define F_DIM 4096
#define N_EXP 8
#define N_TOK 8192
#define NK_ASSIGN (N_TOK * 2)
#define MAX_MB 24  // max M-blocks/expert at BM=128 = 3072 tokens; actual ~2048±50 (>20 sigma)
#define NMB 32     // meta blocks: 8192 tokens / 256 threads

typedef unsigned short u16;
typedef __attribute__((ext_vector_type(8))) short bf16x8;
typedef __attribute__((ext_vector_type(4))) float f32x4;

// RNE float -> bf16 bits (finite inputs only)
__device__ __forceinline__ u16 f2bf(float f) {
  unsigned int u = __float_as_uint(f);
  u += 0x7fffu + ((u >> 16) & 1u);
  return (u16)(u >> 16);
}

// async global->LDS, 16B per lane. lds ptr MUST be wave-uniform (HW adds lane*16).
__device__ __forceinline__ void load16(const u16* g, u16* l) {
  __builtin_amdgcn_global_load_lds(
      (const __attribute__((address_space(1))) void*)g,
      (__attribute__((address_space(3))) void*)l, 16, 0, 0);
}

// ---------------- router: fp32 logits, top-2, gates; also emits xb = bf16(x) --
// NO global atomics (counts come from hist_kernel).
__global__ __launch_bounds__(256) void router_kernel(
    const float* __restrict__ x, const float* __restrict__ rw,
    const float* __restrict__ rb, int* __restrict__ topk_idx,
    float* __restrict__ topk_w, u16* __restrict__ xb) {
  const int lane = threadIdx.x & 63;
  const int wid = threadIdx.x >> 6;
  const int t = blockIdx.x * 4 + wid;  // one wave per token
  const float4* xr = (const float4*)(x + (size_t)t * H_DIM);
  u16* xo = xb + (size_t)t * H_DIM;
  float acc[N_EXP];
#pragma unroll
  for (int e = 0; e < N_EXP; ++e) acc[e] = 0.f;
#pragma unroll
  for (int j = 0; j < 4; ++j) {
    float4 xv = xr[j * 64 + lane];
    // side product: bf16 copy of x (replaces the old gather kernel)
    ushort4 u;
    u.x = f2bf(xv.x); u.y = f2bf(xv.y); u.z = f2bf(xv.z); u.w = f2bf(xv.w);
    *(ushort4*)(xo + (size_t)(j * 64 + lane) * 4) = u;
#pragma unroll
    for (int e = 0; e < N_EXP; ++e) {
      float4 wv = ((const float4*)(rw + e * H_DIM))[j * 64 + lane];
      acc[e] += xv.x * wv.x + xv.y * wv.y + xv.z * wv.z + xv.w * wv.w;
    }
  }
#pragma unroll
  for (int off = 32; off > 0; off >>= 1) {
#pragma unroll
    for (int e = 0; e < N_EXP; ++e) acc[e] += __shfl_xor(acc[e], off);
  }
  if (lane == 0) {
    float lg[N_EXP];
#pragma unroll
    for (int e = 0; e < N_EXP; ++e) lg[e] = acc[e] + rb[e];
    int i0 = 0;
    float b0 = lg[0];
#pragma unroll
    for (int e = 1; e < N_EXP; ++e)
      if (lg[e] > b0) { b0 = lg[e]; i0 = e; }  // strict > : lowest index wins ties
    int i1 = -1;
    float b1 = -3.4e38f;
#pragma unroll
    for (int e = 0; e < N_EXP; ++e)
      if (e != i0 && lg[e] > b1) { b1 = lg[e]; i1 = e; }
    float w0 = 1.f / (1.f + __expf(b1 - b0));  // p0/(p0+p1)
    topk_idx[2 * t] = i0;
    topk_idx[2 * t + 1] = i1;
    topk_w[2 * t] = w0;
    topk_w[2 * t + 1] = 1.f - w0;
  }
}

// ---------------- per-block expert histogram (LDS atomics only) --------------
__global__ __launch_bounds__(256) void hist_kernel(
    const int* __restrict__ topk_idx, int* __restrict__ hist_g) {
  __shared__ int hh[N_EXP];
  const int tid = threadIdx.x;
  if (tid < N_EXP) hh[tid] = 0;
  __syncthreads();
  const int t = blockIdx.x * 256 + tid;
  const int e0 = topk_idx[2 * t], e1 = topk_idx[2 * t + 1];
  atomicAdd(&hh[e0], 1);
  atomicAdd(&hh[e1], 1);
  __syncthreads();
  if (tid < N_EXP) hist_g[blockIdx.x * N_EXP + tid] = hh[tid];
}

// ---------------- scan: offsets[9] + per-(block,expert) bases ----------------
__global__ __launch_bounds__(256) void scan_kernel(
    const int* __restrict__ hist_g, int* __restrict__ offsets,
    int* __restrict__ pos_base) {
  __shared__ int sh[NMB * N_EXP];
  __shared__ int pb[NMB * N_EXP];
  const int tid = threadIdx.x;
  sh[tid] = hist_g[tid];  // 256 == NMB*N_EXP
  __syncthreads();
  if (tid == 0) {
    int tot[N_EXP];
    for (int e = 0; e < N_EXP; ++e) tot[e] = 0;
    for (int b = 0; b < NMB; ++b)
      for (int e = 0; e < N_EXP; ++e) tot[e] += sh[b * N_EXP + e];
    int run = 0;
    for (int e = 0; e < N_EXP; ++e) { offsets[e] = run; run += tot[e]; }
    offsets[N_EXP] = run;  // == 16384
    for (int e = 0; e < N_EXP; ++e) {
      int r = offsets[e];
      for (int b = 0; b < NMB; ++b) { pb[b * N_EXP + e] = r; r += sh[b * N_EXP + e]; }
    }
  }
  __syncthreads();
  pos_base[tid] = pb[tid];
}

// ---------------- scatter: LDS-local cursors, no global atomics --------------
__global__ __launch_bounds__(256) void scatter_kernel(
    const int* __restrict__ topk_idx, const float* __restrict__ topk_w,
    const int* __restrict__ pos_base, int* __restrict__ assign_token,
    float* __restrict__ assign_gate, int* __restrict__ slot_of) {
  __shared__ int cur[N_EXP];
  __shared__ int pb[N_EXP];
  const int tid = threadIdx.x;
  if (tid < N_EXP) {
    cur[tid] = 0;
    pb[tid] = pos_base[blockIdx.x * N_EXP + tid];
  }
  __syncthreads();
  const int t = blockIdx.x * 256 + tid;
#pragma unroll
  for (int k = 0; k < 2; ++k) {
    int e = topk_idx[2 * t + k];
    int local = atomicAdd(&cur[e], 1);
    int pos = pb[e] + local;
    assign_token[pos] = t;
    assign_gate[pos] = topk_w[2 * t + k];
    slot_of[2 * t + k] = pos;  // inverse map for combine
  }
}

// ---------------- fp32 [E][R][C] -> bf16 [E][C][R] (transpose + convert) -----
__global__ __launch_bounds__(256) void transpose_cvt(
    const float* __restrict__ in, u16* __restrict__ out, int R, int C) {
  __shared__ u16 lds[64 * 66];
  const int e = blockIdx.z;
  const float* ip = in + (size_t)e * R * C;
  u16* op = out + (size_t)e * R * C;
  const int c0 = blockIdx.x * 64, r0 = blockIdx.y * 64;
  const int tid = threadIdx.x;
  const int tx = tid & 15, ty = tid >> 4;
#pragma unroll
  for (int i = 0; i < 4; ++i) {
    const int r = ty + i * 16;
    float4 v = *(const float4*)(ip + (size_t)(r0 + r) * C + c0 + tx * 4);
    ushort2 u01, u23;
    u01.x = f2bf(v.x); u01.y = f2bf(v.y);
    u23.x = f2bf(v.z); u23.y = f2bf(v.w);
    *(ushort2*)&lds[r * 66 + tx * 4] = u01;
    *(ushort2*)&lds[r * 66 + tx * 4 + 2] = u23;
  }
  __syncthreads();
  const int lane = tid & 63, wid = tid >> 6;
  const int r8 = lane & 7;
#pragma unroll
  for (int s = 0; s < 2; ++s) {
    const int c = s * 32 + wid * 8 + (lane >> 3);
    union { u16 u[8]; uint4 q; } pk;
#pragma unroll
    for (int k = 0; k < 8; ++k) pk.u[k] = lds[(r8 * 8 + k) * 66 + c];
    *(uint4*)(op + (size_t)(c0 + c) * R + r0 + r8 * 8) = pk.q;
  }
}

// ---------------- grouped GEMM: C[M][N] = A[M][K] * B[N][K]^T ---------------
// Round-0 proven structure: 128x128 tile, BK=32, 4 waves, 16 KB LDS,
// ~4 blocks/CU (implicit m114 wave-level overlap hides the vmcnt drain).
// NEW vs round 0: (a) XCD-aware remap (T1): expert e -> XCD e, M fastest
//   within an XCD's slot range -> B sub-panels stay L2-local (r3 measured
//   FETCH 614->139 MB with this remap family);
// (b) FIRST path stages A rows INDIRECTLY: row slot s -> xb[assign_token[s]]
//   (per-lane global src is legal for global_load_lds; row ptrs hoisted out
//   of the K-loop) -> gather kernel deleted.
// FIRST:  A=xb(indirect), B=w1b, epilogue = tanh-gelu -> bf16 store to h
// !FIRST: A=h (direct),   B=w2b, epilogue = *gate, fp32 store to y_slot
template <int LDA, int LDB, int LDC, int KITERS, int NXB, bool FIRST>
__global__ __launch_bounds__(256) void moe_gemm(
    const u16* __restrict__ Abase, const u16* __restrict__ Bbase,
    u16* __restrict__ hout, float* __restrict__ yout,
    const int* __restrict__ offsets, const float* __restrict__ assign_gate,
    const int* __restrict__ atok) {
  __shared__ __align__(16) u16 As[128 * 32];
  __shared__ __align__(16) u16 Bs[128 * 32];
  // ---- XCD-aware remap: xcd = flat%8 owns expert xcd; mb varies fastest ----
  const int flat = blockIdx.x + NXB * (blockIdx.y + MAX_MB * blockIdx.z);
  const int e = flat & 7;
  const int s = flat >> 3;           // 0 .. NXB*MAX_MB-1
  const int mb = s % MAX_MB;
  const int n0b = s / MAX_MB;        // 0 .. NXB-1
  const int row0 = offsets[e];
  const int cnt = offsets[e + 1] - row0;
  const int mbase = mb * 128;
  if (mbase >= cnt) return;  // block-uniform early exit
  const int mrem = cnt - mbase;
  const int n0 = n0b * 128;
  const int tid = threadIdx.x;
  const int lane = tid & 63;
  const int wid = tid >> 6;
  const int wm = wid & 1, wn = wid >> 1;
  const u16* B = Bbase + (size_t)e * ((size_t)H_DIM * F_DIM);
  const int row16 = lane & 15, quad = lane >> 4;
  const int srow = lane >> 2;        // staging: row within 16-row chunk
  const int scol = (lane & 3) * 8;   // staging: k-col (elements)

  // hoist per-thread A/B row pointers out of the K-loop (removes per-iter
  // 64-bit muls; FIRST adds the assign_token indirection here, once).
  const u16* Arow[2];
  const u16* Brow[2];
#pragma unroll
  for (int i = 0; i < 2; ++i) {
    const int c = wid * 2 + i;           // chunk 0..7 (16 rows x 64B each)
    const int r = c * 16 + srow;
    const int ra = min(r, mrem - 1);     // clamp: stay inside valid A rows
    if (FIRST) {
      const int tok = atok[row0 + mbase + ra];
      Arow[i] = Abase + (size_t)tok * LDA;
    } else {
      Arow[i] = Abase + (size_t)(row0 + mbase + ra) * LDA;
    }
    Brow[i] = B + (size_t)(n0 + r) * LDB;
  }

  f32x4 acc[4][4];
#pragma unroll
  for (int i = 0; i < 4; ++i)
#pragma unroll
    for (int j = 0; j < 4; ++j)
#pragma unroll
      for (int r = 0; r < 4; ++r) acc[i][j][r] = 0.f;

  for (int kt = 0; kt < KITERS; ++kt) {
    const int k0 = kt * 32;
#pragma unroll
    for (int i = 0; i < 2; ++i) {
      const int c = wid * 2 + i;
      load16(Arow[i] + k0 + scol, &As[c * 512]);
      load16(Brow[i] + k0 + scol, &Bs[c * 512]);
    }
    __syncthreads();  // drains vmcnt -> LDS tiles complete
    bf16x8 av[4], bv[4];
#pragma unroll
    for (int mi = 0; mi < 4; ++mi)
      av[mi] = *(const bf16x8*)&As[(wm * 64 + mi * 16 + row16) * 32 + quad * 8];
#pragma unroll
    for (int ni = 0; ni < 4; ++ni)
      bv[ni] = *(const bf16x8*)&Bs[(wn * 64 + ni * 16 + row16) * 32 + quad * 8];
#pragma unroll
    for (int mi = 0; mi < 4; ++mi)
#pragma unroll
      for (int ni = 0; ni < 4; ++ni)
        acc[mi][ni] =
            __builtin_amdgcn_mfma_f32_16x16x32_bf16(av[mi], bv[ni], acc[mi][ni], 0, 0, 0);
    __syncthreads();
  }

  // C/D layout: col = lane&15 (n), row = quad*4 + reg (m)
  if (FIRST) {
    u16* Cp = hout + (size_t)(row0 + mbase) * LDC + n0;
#pragma unroll
    for (int mi = 0; mi < 4; ++mi) {
#pragma unroll
      for (int r = 0; r < 4; ++r) {
        const int lm = wm * 64 + mi * 16 + quad * 4 + r;
        if (lm < mrem) {
#pragma unroll
          for (int ni = 0; ni < 4; ++ni) {
            float v = acc[mi][ni][r];
            // tanh-approx gelu via sigmoid: v * sigmoid(2*sqrt(2/pi)*(v+0.044715v^3))
            float t = v * (0.7978845608028654f + 0.0356774081363f * v * v);
            v = v / (1.f + __expf(-2.f * t));
            Cp[(size_t)lm * LDC + (wn * 64 + ni * 16 + row16)] = f2bf(v);
          }
        }
      }
    }
  } else {
#pragma unroll
    for (int mi = 0; mi < 4; ++mi) {
#pragma unroll
      for (int r = 0; r < 4; ++r) {
        const int lm = wm * 64 + mi * 16 + quad * 4 + r;
        if (lm < mrem) {
          const int slot = row0 + mbase + lm;
          const float g = assign_gate[slot];
          float* orow = yout + (size_t)slot * LDC + n0;
#pragma unroll
          for (int ni = 0; ni < 4; ++ni)
            orow[wn * 64 + ni * 16 + row16] = acc[mi][ni][r] * g;
        }
      }
    }
  }
}

// ---------------- combine: out[t] = y_slot[s0] + y_slot[s1] ------------------
__global__ __launch_bounds__(256) void combine_kernel(
    const float* __restrict__ ys, const int* __restrict__ slot_of,
    float* __restrict__ out) {
  const int t = blockIdx.x;
  const int s0 = slot_of[2 * t], s1 = slot_of[2 * t + 1];
  const int i = threadIdx.x;
  float4 a = ((const float4*)(ys + (size_t)s0 * H_DIM))[i];
  float4 b = ((const float4*)(ys + (size_t)s1 * H_DIM))[i];
  float4 o;
  o.x = a.x + b.x; o.y = a.y + b.y; o.z = a.z + b.z; o.w = a.w + b.w;
  ((float4*)(out + (size_t)t * H_DIM))[i] = o;
}

extern "C" void kernel_launch(void* const* d_in, const int* in_sizes, int n_in,
                              void* d_out, int out_size, void* d_ws, size_t ws_size,
                              hipStream_t stream) {
  const float* x = (const float*)d_in[0];
  const float* rw = (const float*)d_in[1];
  const float* rb = (const float*)d_in[2];
  const float* w1 = (const float*)d_in[3];
  const float* w2 = (const float*)d_in[4];
  float* out = (float*)d_out;

  char* ws = (char*)d_ws;
  // workspace layout (~302.4 MB total)
  u16* w1b = (u16*)(ws);                        // [E][F][H] bf16   67,108,864 B
  float* y_slot = (float*)(ws);                 // [16384][H] fp32 -- ALIASES w1b
                                                // (w1b dead after GEMM1; GEMM2 writes here)
  u16* w2b = (u16*)(ws + 67108864);             // [E][H][F] bf16   67,108,864 B
  u16* xb = (u16*)(ws + 134217728);             // [8192][H] bf16   16,777,216 B (was xg)
  u16* h = (u16*)(ws + 167772160);              // [16384][F] bf16 134,217,728 B
  // hist/pos_base borrow the head of the h region (dead before GEMM1 writes h)
  int* hist_g = (int*)(ws + 167772160);         // [32][8] ints (1 KB)
  int* pos_base = hist_g + NMB * N_EXP;         // [32][8] ints (1 KB)
  char* meta = ws + 301989888;
  int* offsets = (int*)(meta + 64);             // 9 ints
  int* topk_idx = (int*)(meta + 128);           // 16384 ints
  float* topk_w = (float*)(meta + 128 + 65536);
  int* assign_token = (int*)(meta + 128 + 131072);
  float* assign_gate = (float*)(meta + 128 + 196608);
  int* slot_of = (int*)(meta + 128 + 262144);

  router_kernel<<<N_TOK / 4, 256, 0, stream>>>(x, rw, rb, topk_idx, topk_w, xb);
  hist_kernel<<<NMB, 256, 0, stream>>>(topk_idx, hist_g);
  scan_kernel<<<1, 256, 0, stream>>>(hist_g, offsets, pos_base);
  scatter_kernel<<<NMB, 256, 0, stream>>>(topk_idx, topk_w, pos_base,
                                          assign_token, assign_gate, slot_of);
  // w1 [E][1024][4096] -> w1b [E][4096][1024]
  transpose_cvt<<<dim3(F_DIM / 64, H_DIM / 64, N_EXP), 256, 0, stream>>>(w1, w1b, H_DIM, F_DIM);
  // w2 [E][4096][1024] -> w2b [E][1024][4096]
  transpose_cvt<<<dim3(H_DIM / 64, F_DIM / 64, N_EXP), 256, 0, stream>>>(w2, w2b, F_DIM, H_DIM);

  // GEMM1: [cnt_e][1024] (indirect rows of xb) @ [4096][1024]^T -> gelu -> h
  moe_gemm<H_DIM, H_DIM, F_DIM, H_DIM / 32, F_DIM / 128, true>
      <<<dim3(F_DIM / 128, MAX_MB, N_EXP), 256, 0, stream>>>(
          xb, w1b, h, nullptr, offsets, assign_gate, assign_token);
  // GEMM2: [cnt_e][4096] @ [1024][4096]^T -> *gate -> y_slot [16384][1024]
  moe_gemm<F_DIM, F_DIM, H_DIM, F_DIM / 32, H_DIM / 128, false>
      <<<dim3(H_DIM / 128, MAX_MB, N_EXP), 256, 0, stream>>>(
          h, w2b, nullptr, y_slot, offsets, assign_gate, nullptr);
  // out[t] = y_slot[slot0(t)] + y_slot[slot1(t)]
  combine_kernel<<<N_TOK, 256, 0, stream>>>(y_slot, slot_of, out);

  (void)in_sizes; (void)n_in; (void)ws_size;
}